// Round 5
// baseline (345.185 us; speedup 1.0000x reference)
//
#include <hip/hip_runtime.h>
#include <math.h>

#define D 64

typedef _Float16 hf;
typedef _Float16 hf2 __attribute__((ext_vector_type(2)));

__device__ inline float fdot2f(hf2 a, hf2 b, float c) {
#if __has_builtin(__builtin_amdgcn_fdot2)
    return __builtin_amdgcn_fdot2(a, b, c, false);
#else
    return (float)a[0] * (float)b[0] + (float)a[1] * (float)b[1] + c;
#endif
}

// ---------------- Kernel 1: per-node linear transforms (fp16 weights, fdot2) ----------------
__global__ __launch_bounds__(512) void node_pre_kernel(
    const float* __restrict__ h,
    const float* __restrict__ W_att,
    const float* __restrict__ W_p,
    const float* __restrict__ W_pp,
    const float* __restrict__ phi_w,
    const float* __restrict__ phi_b,
    const float* __restrict__ fdef_w,
    const float* __restrict__ fdef_b,
    hf2* __restrict__ AP16,
    hf* __restrict__ s6,
    hf* __restrict__ PP16,
    hf* __restrict__ PHI16,
    float* __restrict__ psi,
    int nNodes)
{
    __shared__ hf2 sW2[4][32][D];        // 32 KB
    __shared__ hf  hrowh[8][D];
    __shared__ float sPhib[D];
    __shared__ float sFdef[D];

    const int tid = threadIdx.x;
    const float* Wm[4] = { W_att, W_p, W_pp, phi_w };
    for (int idx = tid; idx < 4 * 32 * D; idx += 512) {
        const int m  = idx >> 11;
        const int k2 = (idx >> 6) & 31;
        const int j  = idx & 63;
        sW2[m][k2][j] = hf2{(hf)Wm[m][(2 * k2) * D + j], (hf)Wm[m][(2 * k2 + 1) * D + j]};
    }
    if (tid < D) { sPhib[tid] = phi_b[tid]; sFdef[tid] = fdef_w[tid]; }
    __syncthreads();
    const float fb = fdef_b[0];

    const int g = tid >> 6;
    const int j = tid & 63;

    for (int n0 = blockIdx.x * 8; n0 < nNodes; n0 += gridDim.x * 8) {
        const int n = n0 + g;
        float hj = 0.f;
        __syncthreads();
        if (n < nNodes) {
            hj = h[(size_t)n * D + j];
            hrowh[g][j] = (hf)hj;
        }
        __syncthreads();
        if (n < nNodes) {
            float a = 0.f, p = 0.f, pp = 0.f, ph = sPhib[j];
            const hf2* hr = (const hf2*)hrowh[g];
            #pragma unroll
            for (int k2 = 0; k2 < 32; ++k2) {
                const hf2 hb = hr[k2];
                a  = fdot2f(sW2[0][k2][j], hb, a);
                p  = fdot2f(sW2[1][k2][j], hb, p);
                pp = fdot2f(sW2[2][k2][j], hb, pp);
                ph = fdot2f(sW2[3][k2][j], hb, ph);
            }
            const size_t base = (size_t)n * D + j;
            AP16[base]  = hf2{(hf)a, (hf)p};
            PP16[base]  = (hf)pp;
            PHI16[base] = (hf)ph;
            if (j < 8) s6[(size_t)n * 8 + j] = (hf)(j < 6 ? hj : 0.f);
            float ps = hj * sFdef[j];
            #pragma unroll
            for (int off = 32; off >= 1; off >>= 1) ps += __shfl_xor(ps, off, 64);
            if (j == 0) psi[n] = ps + fb;
        }
    }
}

// ---------------- CSR build ----------------
__global__ __launch_bounds__(256) void hist_kernel(
    const int* __restrict__ tgtI, int* __restrict__ cnt, int* __restrict__ rank, int nEdges)
{
    const int e = blockIdx.x * 256 + threadIdx.x;
    if (e < nEdges) rank[e] = atomicAdd(&cnt[tgtI[e]], 1);
}

__global__ __launch_bounds__(1024) void scan_kernel(
    const int* __restrict__ cnt, int* __restrict__ rowstart, int nNodes, int nEdges)
{
    __shared__ int sums[1024];
    const int tid = threadIdx.x;
    const int per = (nNodes + 1023) / 1024;
    const int beg = tid * per;
    const int end = min(beg + per, nNodes);
    int s = 0;
    for (int i = beg; i < end; ++i) s += cnt[i];
    sums[tid] = s;
    __syncthreads();
    for (int off = 1; off < 1024; off <<= 1) {
        int add = (tid >= off) ? sums[tid - off] : 0;
        __syncthreads();
        sums[tid] += add;
        __syncthreads();
    }
    int run = sums[tid] - s;
    for (int i = beg; i < end; ++i) { rowstart[i] = run; run += cnt[i]; }
    if (tid == 1023) rowstart[nNodes] = nEdges;
}

__global__ __launch_bounds__(256) void scatter_src_kernel(
    const int* __restrict__ srcI,
    const int* __restrict__ tgtI,
    const int* __restrict__ rank,
    const int* __restrict__ rowstart,
    int* __restrict__ src_sorted,
    int nEdges)
{
    const int e = blockIdx.x * 256 + threadIdx.x;
    if (e >= nEdges) return;
    src_sorted[rowstart[tgtI[e]] + rank[e]] = srcI[e];
}

// ---------------- Pass 1 over tgt-CSR: one wave per tgt node, 2x unrolled ----------------
__global__ __launch_bounds__(256) void pass1_csr_kernel(
    const int* __restrict__ rowstart,
    const int* __restrict__ src_sorted,
    const float* __restrict__ h,
    const hf2* __restrict__ AP16,
    const hf* __restrict__ s6,
    const hf* __restrict__ PP16,
    const float* __restrict__ psi,
    float* __restrict__ alpha_sorted,
    float* __restrict__ inv_den,
    float* __restrict__ beta_den,
    float* __restrict__ sum_num,
    int nNodes)
{
    const int wav = threadIdx.x >> 6;
    const int lane64 = threadIdx.x & 63;
    const int grp = lane64 >> 4;   // 4 edge-groups per wave
    const int l = lane64 & 15;     // 16 lanes per edge, 4 dims each

    for (int n = blockIdx.x * 4 + wav; n < nNodes; n += gridDim.x * 4) {
        const int beg = rowstart[n];
        const int end = rowstart[n + 1];
        const float4 htv = ((const float4*)(h + (size_t)n * D))[l];
        const float2 ppraw = *reinterpret_cast<const float2*>(
            (const char*)PP16 + ((size_t)n << 7) + (l << 3));
        const hf* ppq = (const hf*)&ppraw;
        const float pp0 = ppq[0], pp1 = ppq[1], pp2 = ppq[2], pp3 = ppq[3];
        const float enpsi = __expf(-psi[n]);
        float aden = 0.f;

        auto edge_dot = [&](int s, float& acc1, float& acc2) {
            const float4 raw = *reinterpret_cast<const float4*>(
                (const char*)AP16 + ((size_t)s << 8) + (l << 4));
            const hf* q = (const hf*)&raw;
            acc1 = (float)q[0] * htv.x + (float)q[2] * htv.y
                 + (float)q[4] * htv.z + (float)q[6] * htv.w;
            acc2 = (float)q[1] * pp0 + (float)q[3] * pp1
                 + (float)q[5] * pp2 + (float)q[7] * pp3;
            if (l < 2) {
                const float2 sraw = *reinterpret_cast<const float2*>(
                    (const char*)s6 + ((size_t)s << 4) + (l << 3));
                const hf* sq = (const hf*)&sraw;
                acc1 += (float)sq[0] * htv.x + (float)sq[1] * htv.y
                      + (float)sq[2] * htv.z + (float)sq[3] * htv.w;
            }
        };

        int k = beg + grp;
        // 2x unrolled: two independent row-gathers in flight per group
        for (; k + 4 < end; k += 8) {
            const int sA = src_sorted[k];
            const int sB = src_sorted[k + 4];
            float a1, a2, b1, b2;
            edge_dot(sA, a1, a2);
            edge_dot(sB, b1, b2);
            #pragma unroll
            for (int off = 8; off >= 1; off >>= 1) {
                a1 += __shfl_xor(a1, off, 64);
                a2 += __shfl_xor(a2, off, 64);
                b1 += __shfl_xor(b1, off, 64);
                b2 += __shfl_xor(b2, off, 64);
            }
            if (l == 0) {
                const float anA = __expf(a1);
                const float bnA = __expf(a2);
                const float anB = __expf(b1);
                const float bnB = __expf(b2);
                alpha_sorted[k]     = anA;
                alpha_sorted[k + 4] = anB;
                aden += anA + anB;
                atomicAdd(&beta_den[sA], bnA);
                atomicAdd(&sum_num[sA], bnA * enpsi);
                atomicAdd(&beta_den[sB], bnB);
                atomicAdd(&sum_num[sB], bnB * enpsi);
            }
        }
        if (k < end) {
            const int s = src_sorted[k];
            float a1, a2;
            edge_dot(s, a1, a2);
            #pragma unroll
            for (int off = 8; off >= 1; off >>= 1) {
                a1 += __shfl_xor(a1, off, 64);
                a2 += __shfl_xor(a2, off, 64);
            }
            if (l == 0) {
                const float an = __expf(a1);
                const float bn = __expf(a2);
                alpha_sorted[k] = an;
                aden += an;
                atomicAdd(&beta_den[s], bn);
                atomicAdd(&sum_num[s], bn * enpsi);
            }
        }

        float ad = aden;
        #pragma unroll
        for (int off = 32; off >= 1; off >>= 1) ad += __shfl_xor(ad, off, 64);
        if (lane64 == 0) inv_den[n] = 1.0f / (ad + 1e-9f);
    }
}

// ---------------- Node mid: fold w1m into PHI -> PHIw16 ----------------
__global__ __launch_bounds__(256) void node_mid_kernel(
    const float* __restrict__ beta_den,
    const float* __restrict__ sum_num,
    const hf* __restrict__ PHI16,
    hf* __restrict__ PHIw16,
    int nNodes)
{
    const int wav = threadIdx.x >> 6;
    const int lane = threadIdx.x & 63;
    for (int n = blockIdx.x * 4 + wav; n < nNodes; n += gridDim.x * 4) {
        const float st = sum_num[n] / (beta_den[n] + 1e-9f);
        const float d = -logf(st + 1e-8f);
        const float w1m = 1.0f - 1.0f / (1.0f + __expf(-(d - 0.5f)));
        const size_t idx = (size_t)n * D + lane;
        PHIw16[idx] = (hf)((float)PHI16[idx] * w1m);
    }
}

// ---------------- Fused: gather m_att + final matmuls + relu + residual + LN ----------------
__global__ __launch_bounds__(512) void final_fused_kernel(
    const int* __restrict__ rowstart,
    const int* __restrict__ src_sorted,
    const float* __restrict__ alpha_sorted,
    const float* __restrict__ inv_den,
    const hf* __restrict__ PHIw16,
    const float* __restrict__ h,
    const float* __restrict__ W_self_w, const float* __restrict__ W_self_b,
    const float* __restrict__ W_A_w,    const float* __restrict__ W_A_b,
    const float* __restrict__ W_str_w,  const float* __restrict__ W_str_b,
    const float* __restrict__ ln_g,     const float* __restrict__ ln_b,
    float* __restrict__ out,
    int nNodes)
{
    __shared__ hf2 sWs2[32][D];     // 8 KB
    __shared__ hf2 sWa2[32][D];     // 8 KB
    __shared__ float sWstr[6 * D];
    __shared__ float sBias[D];
    __shared__ float sG[D], sB[D];
    __shared__ hf hrowh[8][D];
    __shared__ hf mrowh[8][D];

    const int tid = threadIdx.x;
    for (int idx = tid; idx < 32 * D; idx += 512) {
        const int k2 = idx >> 6, j = idx & 63;
        sWs2[k2][j] = hf2{(hf)W_self_w[(2 * k2) * D + j], (hf)W_self_w[(2 * k2 + 1) * D + j]};
        sWa2[k2][j] = hf2{(hf)W_A_w[(2 * k2) * D + j],    (hf)W_A_w[(2 * k2 + 1) * D + j]};
    }
    for (int i = tid; i < 6 * D; i += 512) sWstr[i] = W_str_w[i];
    if (tid < D) {
        sBias[tid] = W_self_b[tid] + W_A_b[tid] + W_str_b[tid];
        sG[tid] = ln_g[tid];
        sB[tid] = ln_b[tid];
    }
    __syncthreads();

    const int g = tid >> 6, j = tid & 63;
    for (int n0 = blockIdx.x * 8; n0 < nNodes; n0 += gridDim.x * 8) {
        const int n = n0 + g;
        float hj = 0.f;
        __syncthreads();
        if (n < nNodes) {
            const int beg = rowstart[n];
            const int end = rowstart[n + 1];
            float acc = 0.f;
            int k = beg;
            for (; k + 3 < end; k += 4) {
                const int   s0 = src_sorted[k],     s1 = src_sorted[k + 1];
                const int   s2 = src_sorted[k + 2], s3 = src_sorted[k + 3];
                const float c0 = alpha_sorted[k],     c1 = alpha_sorted[k + 1];
                const float c2 = alpha_sorted[k + 2], c3 = alpha_sorted[k + 3];
                acc += c0 * (float)PHIw16[(size_t)s0 * D + j]
                     + c1 * (float)PHIw16[(size_t)s1 * D + j]
                     + c2 * (float)PHIw16[(size_t)s2 * D + j]
                     + c3 * (float)PHIw16[(size_t)s3 * D + j];
            }
            for (; k < end; ++k)
                acc += alpha_sorted[k] * (float)PHIw16[(size_t)src_sorted[k] * D + j];

            hj = h[(size_t)n * D + j];
            hrowh[g][j] = (hf)hj;
            mrowh[g][j] = (hf)(acc * inv_den[n]);
        }
        __syncthreads();
        if (n < nNodes) {
            float acc = sBias[j];
            const hf2* hr = (const hf2*)hrowh[g];
            const hf2* mr = (const hf2*)mrowh[g];
            #pragma unroll
            for (int k2 = 0; k2 < 32; ++k2) {
                acc = fdot2f(sWs2[k2][j], hr[k2], acc);
                acc = fdot2f(sWa2[k2][j], mr[k2], acc);
            }
            #pragma unroll
            for (int k = 0; k < 6; ++k)
                acc += (float)hrowh[g][k] * sWstr[k * D + j];

            float pre = fmaxf(acc, 0.f) + hj;

            float mu = pre;
            #pragma unroll
            for (int off = 32; off >= 1; off >>= 1) mu += __shfl_xor(mu, off, 64);
            mu *= (1.0f / 64.0f);
            const float diff = pre - mu;
            float v = diff * diff;
            #pragma unroll
            for (int off = 32; off >= 1; off >>= 1) v += __shfl_xor(v, off, 64);
            v *= (1.0f / 64.0f);
            out[(size_t)n * D + j] = diff * rsqrtf(v + 1e-5f) * sG[j] + sB[j];
        }
    }
}

extern "C" void kernel_launch(void* const* d_in, const int* in_sizes, int n_in,
                              void* d_out, int out_size, void* d_ws, size_t ws_size,
                              hipStream_t stream) {
    const int* edge       = (const int*)d_in[0];
    const float* h        = (const float*)d_in[1];
    const float* W_att    = (const float*)d_in[2];
    const float* phi_w    = (const float*)d_in[3];
    const float* phi_b    = (const float*)d_in[4];
    const float* W_p      = (const float*)d_in[5];
    const float* W_pp     = (const float*)d_in[6];
    const float* fdef_w   = (const float*)d_in[7];
    const float* fdef_b   = (const float*)d_in[8];
    const float* W_self_w = (const float*)d_in[9];
    const float* W_self_b = (const float*)d_in[10];
    const float* W_A_w    = (const float*)d_in[11];
    const float* W_A_b    = (const float*)d_in[12];
    const float* W_str_w  = (const float*)d_in[13];
    const float* W_str_b  = (const float*)d_in[14];
    const float* ln_g     = (const float*)d_in[15];
    const float* ln_b     = (const float*)d_in[16];

    const int E = in_sizes[0] / 2;
    const int nNodes = in_sizes[1] / D;
    const int* srcI = edge;
    const int* tgtI = edge + E;

    char* ws = (char*)d_ws;
    size_t off = 0;
    auto alloc = [&](size_t bytes) { char* p = ws + off; off = (off + bytes + 255) & ~(size_t)255; return p; };

    int*    cnt       = (int*)   alloc((size_t)nNodes * 4);
    float*  beta_den  = (float*) alloc((size_t)nNodes * 4);
    float*  sum_num   = (float*) alloc((size_t)nNodes * 4);
    const size_t zero_bytes = off;
    hf2*    AP16      = (hf2*)   alloc((size_t)nNodes * D * 4);
    hf*     s6        = (hf*)    alloc((size_t)nNodes * 8 * 2);
    hf*     PP16      = (hf*)    alloc((size_t)nNodes * D * 2);
    hf*     PHI16     = (hf*)    alloc((size_t)nNodes * D * 2);
    hf*     PHIw16    = (hf*)    alloc((size_t)nNodes * D * 2);
    float*  psi       = (float*) alloc((size_t)nNodes * 4);
    float*  inv_den   = (float*) alloc((size_t)nNodes * 4);
    int*    rank      = (int*)   alloc((size_t)E * 4);
    int*    rowstart  = (int*)   alloc(((size_t)nNodes + 1) * 4);
    int*    src_sorted= (int*)   alloc((size_t)E * 4);
    float*  alpha_sorted = (float*)alloc((size_t)E * 4);

    hipMemsetAsync(d_ws, 0, zero_bytes, stream);

    node_pre_kernel<<<2048, 512, 0, stream>>>(
        h, W_att, W_p, W_pp, phi_w, phi_b, fdef_w, fdef_b,
        AP16, s6, PP16, PHI16, psi, nNodes);

    hist_kernel<<<(E + 255) / 256, 256, 0, stream>>>(tgtI, cnt, rank, E);

    scan_kernel<<<1, 1024, 0, stream>>>(cnt, rowstart, nNodes, E);

    scatter_src_kernel<<<(E + 255) / 256, 256, 0, stream>>>(
        srcI, tgtI, rank, rowstart, src_sorted, E);

    pass1_csr_kernel<<<(nNodes + 3) / 4, 256, 0, stream>>>(
        rowstart, src_sorted, h, AP16, s6, PP16, psi,
        alpha_sorted, inv_den, beta_den, sum_num, nNodes);

    node_mid_kernel<<<(nNodes + 3) / 4, 256, 0, stream>>>(
        beta_den, sum_num, PHI16, PHIw16, nNodes);

    final_fused_kernel<<<2048, 512, 0, stream>>>(
        rowstart, src_sorted, alpha_sorted, inv_den, PHIw16, h,
        W_self_w, W_self_b, W_A_w, W_A_b, W_str_w, W_str_b,
        ln_g, ln_b, (float*)d_out, nNodes);
}

// Round 6
// 333.424 us; speedup vs baseline: 1.0353x; 1.0353x over previous
//
#include <hip/hip_runtime.h>
#include <math.h>

#define D 64

typedef _Float16 hf;
typedef _Float16 hf2 __attribute__((ext_vector_type(2)));

__device__ inline float fdot2f(hf2 a, hf2 b, float c) {
#if __has_builtin(__builtin_amdgcn_fdot2)
    return __builtin_amdgcn_fdot2(a, b, c, false);
#else
    return (float)a[0] * (float)b[0] + (float)a[1] * (float)b[1] + c;
#endif
}

// ---------------- Kernel 1: per-node linear transforms (fp16 weights, fdot2) ----------------
__global__ __launch_bounds__(512) void node_pre_kernel(
    const float* __restrict__ h,
    const float* __restrict__ W_att,
    const float* __restrict__ W_p,
    const float* __restrict__ W_pp,
    const float* __restrict__ phi_w,
    const float* __restrict__ phi_b,
    const float* __restrict__ fdef_w,
    const float* __restrict__ fdef_b,
    hf2* __restrict__ AP16,
    hf* __restrict__ s6,
    hf* __restrict__ PP16,
    hf* __restrict__ PHI16,
    float* __restrict__ psi,
    int nNodes)
{
    __shared__ hf2 sW2[4][32][D];        // 32 KB
    __shared__ hf  hrowh[8][D];
    __shared__ float sPhib[D];
    __shared__ float sFdef[D];

    const int tid = threadIdx.x;
    const float* Wm[4] = { W_att, W_p, W_pp, phi_w };
    for (int idx = tid; idx < 4 * 32 * D; idx += 512) {
        const int m  = idx >> 11;
        const int k2 = (idx >> 6) & 31;
        const int j  = idx & 63;
        sW2[m][k2][j] = hf2{(hf)Wm[m][(2 * k2) * D + j], (hf)Wm[m][(2 * k2 + 1) * D + j]};
    }
    if (tid < D) { sPhib[tid] = phi_b[tid]; sFdef[tid] = fdef_w[tid]; }
    __syncthreads();
    const float fb = fdef_b[0];

    const int g = tid >> 6;
    const int j = tid & 63;

    for (int n0 = blockIdx.x * 8; n0 < nNodes; n0 += gridDim.x * 8) {
        const int n = n0 + g;
        float hj = 0.f;
        __syncthreads();
        if (n < nNodes) {
            hj = h[(size_t)n * D + j];
            hrowh[g][j] = (hf)hj;
        }
        __syncthreads();
        if (n < nNodes) {
            float a = 0.f, p = 0.f, pp = 0.f, ph = sPhib[j];
            const hf2* hr = (const hf2*)hrowh[g];
            #pragma unroll
            for (int k2 = 0; k2 < 32; ++k2) {
                const hf2 hb = hr[k2];
                a  = fdot2f(sW2[0][k2][j], hb, a);
                p  = fdot2f(sW2[1][k2][j], hb, p);
                pp = fdot2f(sW2[2][k2][j], hb, pp);
                ph = fdot2f(sW2[3][k2][j], hb, ph);
            }
            const size_t base = (size_t)n * D + j;
            AP16[base]  = hf2{(hf)a, (hf)p};
            PP16[base]  = (hf)pp;
            PHI16[base] = (hf)ph;
            if (j < 8) s6[(size_t)n * 8 + j] = (hf)(j < 6 ? hj : 0.f);
            float ps = hj * sFdef[j];
            #pragma unroll
            for (int off = 32; off >= 1; off >>= 1) ps += __shfl_xor(ps, off, 64);
            if (j == 0) psi[n] = ps + fb;
        }
    }
}

// ---------------- CSR build ----------------
__global__ __launch_bounds__(256) void hist_kernel(
    const int* __restrict__ tgtI, int* __restrict__ cnt, int* __restrict__ rank, int nEdges)
{
    const int e = blockIdx.x * 256 + threadIdx.x;
    if (e < nEdges) rank[e] = atomicAdd(&cnt[tgtI[e]], 1);
}

__global__ __launch_bounds__(1024) void scan_kernel(
    const int* __restrict__ cnt, int* __restrict__ rowstart, int nNodes, int nEdges)
{
    __shared__ int sums[1024];
    const int tid = threadIdx.x;
    const int per = (nNodes + 1023) / 1024;
    const int beg = tid * per;
    const int end = min(beg + per, nNodes);
    int s = 0;
    for (int i = beg; i < end; ++i) s += cnt[i];
    sums[tid] = s;
    __syncthreads();
    for (int off = 1; off < 1024; off <<= 1) {
        int add = (tid >= off) ? sums[tid - off] : 0;
        __syncthreads();
        sums[tid] += add;
        __syncthreads();
    }
    int run = sums[tid] - s;
    for (int i = beg; i < end; ++i) { rowstart[i] = run; run += cnt[i]; }
    if (tid == 1023) rowstart[nNodes] = nEdges;
}

__global__ __launch_bounds__(256) void scatter_src_kernel(
    const int* __restrict__ srcI,
    const int* __restrict__ tgtI,
    const int* __restrict__ rank,
    const int* __restrict__ rowstart,
    int* __restrict__ src_sorted,
    int nEdges)
{
    const int e = blockIdx.x * 256 + threadIdx.x;
    if (e >= nEdges) return;
    src_sorted[rowstart[tgtI[e]] + rank[e]] = srcI[e];
}

// ---------------- Pass 1 over tgt-CSR: 8 lanes/edge, forced 2x MLP ----------------
__global__ __launch_bounds__(256) void pass1_csr_kernel(
    const int* __restrict__ rowstart,
    const int* __restrict__ src_sorted,
    const float* __restrict__ h,
    const hf2* __restrict__ AP16,
    const hf* __restrict__ s6,
    const hf* __restrict__ PP16,
    const float* __restrict__ psi,
    float* __restrict__ alpha_sorted,
    float* __restrict__ inv_den,
    float* __restrict__ beta_den,
    float* __restrict__ sum_num,
    int nNodes)
{
    const int wav = threadIdx.x >> 6;
    const int lane64 = threadIdx.x & 63;
    const int grp = lane64 >> 3;   // 8 edge-groups per wave
    const int l = lane64 & 7;      // 8 lanes per edge, 2 chunks of 4 dims each

    for (int n = blockIdx.x * 4 + wav; n < nNodes; n += gridDim.x * 4) {
        const int beg = rowstart[n];
        const int end = rowstart[n + 1];
        // own rows: dims 4l..4l+3 (chunk l) and dims 4(l+8)..4(l+8)+3 (chunk l+8)
        const float4 ht0 = ((const float4*)(h + (size_t)n * D))[l];
        const float4 ht1 = ((const float4*)(h + (size_t)n * D))[l + 8];
        const float2 pr0 = ((const float2*)(PP16 + (size_t)n * D))[l];
        const float2 pr1 = ((const float2*)(PP16 + (size_t)n * D))[l + 8];
        const hf* pq0 = (const hf*)&pr0;
        const hf* pq1 = (const hf*)&pr1;
        const float pp00 = pq0[0], pp01 = pq0[1], pp02 = pq0[2], pp03 = pq0[3];
        const float pp10 = pq1[0], pp11 = pq1[1], pp12 = pq1[2], pp13 = pq1[3];
        const float enpsi = __expf(-psi[n]);
        float aden = 0.f;

        int k = beg + grp;
        // main: two edges (k, k+8) with all four row-gathers issued up front
        for (; k + 8 < end; k += 16) {
            const int sA = src_sorted[k];
            const int sB = src_sorted[k + 8];
            const char* baseA = (const char*)AP16 + ((size_t)sA << 8) + (l << 4);
            const char* baseB = (const char*)AP16 + ((size_t)sB << 8) + (l << 4);
            const float4 rA0 = *(const float4*)(baseA);
            const float4 rA1 = *(const float4*)(baseA + 128);
            const float4 rB0 = *(const float4*)(baseB);
            const float4 rB1 = *(const float4*)(baseB + 128);
            float sdA = 0.f, sdB = 0.f;
            if (l < 2) {
                const float2 s6A = *(const float2*)((const char*)s6 + ((size_t)sA << 4) + (l << 3));
                const float2 s6B = *(const float2*)((const char*)s6 + ((size_t)sB << 4) + (l << 3));
                const hf* qa = (const hf*)&s6A;
                const hf* qb = (const hf*)&s6B;
                sdA = (float)qa[0] * ht0.x + (float)qa[1] * ht0.y
                    + (float)qa[2] * ht0.z + (float)qa[3] * ht0.w;
                sdB = (float)qb[0] * ht0.x + (float)qb[1] * ht0.y
                    + (float)qb[2] * ht0.z + (float)qb[3] * ht0.w;
            }
            const hf* qA0 = (const hf*)&rA0;
            const hf* qA1 = (const hf*)&rA1;
            const hf* qB0 = (const hf*)&rB0;
            const hf* qB1 = (const hf*)&rB1;
            float a1 = sdA
                     + (float)qA0[0] * ht0.x + (float)qA0[2] * ht0.y
                     + (float)qA0[4] * ht0.z + (float)qA0[6] * ht0.w
                     + (float)qA1[0] * ht1.x + (float)qA1[2] * ht1.y
                     + (float)qA1[4] * ht1.z + (float)qA1[6] * ht1.w;
            float a2 = (float)qA0[1] * pp00 + (float)qA0[3] * pp01
                     + (float)qA0[5] * pp02 + (float)qA0[7] * pp03
                     + (float)qA1[1] * pp10 + (float)qA1[3] * pp11
                     + (float)qA1[5] * pp12 + (float)qA1[7] * pp13;
            float b1 = sdB
                     + (float)qB0[0] * ht0.x + (float)qB0[2] * ht0.y
                     + (float)qB0[4] * ht0.z + (float)qB0[6] * ht0.w
                     + (float)qB1[0] * ht1.x + (float)qB1[2] * ht1.y
                     + (float)qB1[4] * ht1.z + (float)qB1[6] * ht1.w;
            float b2 = (float)qB0[1] * pp00 + (float)qB0[3] * pp01
                     + (float)qB0[5] * pp02 + (float)qB0[7] * pp03
                     + (float)qB1[1] * pp10 + (float)qB1[3] * pp11
                     + (float)qB1[5] * pp12 + (float)qB1[7] * pp13;
            #pragma unroll
            for (int off = 4; off >= 1; off >>= 1) {
                a1 += __shfl_xor(a1, off, 64);
                a2 += __shfl_xor(a2, off, 64);
                b1 += __shfl_xor(b1, off, 64);
                b2 += __shfl_xor(b2, off, 64);
            }
            if (l == 0) {
                const float anA = __expf(a1);
                const float bnA = __expf(a2);
                const float anB = __expf(b1);
                const float bnB = __expf(b2);
                alpha_sorted[k]     = anA;
                alpha_sorted[k + 8] = anB;
                aden += anA + anB;
                atomicAdd(&beta_den[sA], bnA);
                atomicAdd(&sum_num[sA], bnA * enpsi);
                atomicAdd(&beta_den[sB], bnB);
                atomicAdd(&sum_num[sB], bnB * enpsi);
            }
        }
        if (k < end) {
            const int s = src_sorted[k];
            const char* base = (const char*)AP16 + ((size_t)s << 8) + (l << 4);
            const float4 r0 = *(const float4*)(base);
            const float4 r1 = *(const float4*)(base + 128);
            float sd = 0.f;
            if (l < 2) {
                const float2 s6r = *(const float2*)((const char*)s6 + ((size_t)s << 4) + (l << 3));
                const hf* q = (const hf*)&s6r;
                sd = (float)q[0] * ht0.x + (float)q[1] * ht0.y
                   + (float)q[2] * ht0.z + (float)q[3] * ht0.w;
            }
            const hf* q0 = (const hf*)&r0;
            const hf* q1 = (const hf*)&r1;
            float a1 = sd
                     + (float)q0[0] * ht0.x + (float)q0[2] * ht0.y
                     + (float)q0[4] * ht0.z + (float)q0[6] * ht0.w
                     + (float)q1[0] * ht1.x + (float)q1[2] * ht1.y
                     + (float)q1[4] * ht1.z + (float)q1[6] * ht1.w;
            float a2 = (float)q0[1] * pp00 + (float)q0[3] * pp01
                     + (float)q0[5] * pp02 + (float)q0[7] * pp03
                     + (float)q1[1] * pp10 + (float)q1[3] * pp11
                     + (float)q1[5] * pp12 + (float)q1[7] * pp13;
            #pragma unroll
            for (int off = 4; off >= 1; off >>= 1) {
                a1 += __shfl_xor(a1, off, 64);
                a2 += __shfl_xor(a2, off, 64);
            }
            if (l == 0) {
                const float an = __expf(a1);
                const float bn = __expf(a2);
                alpha_sorted[k] = an;
                aden += an;
                atomicAdd(&beta_den[s], bn);
                atomicAdd(&sum_num[s], bn * enpsi);
            }
        }

        float ad = aden;
        #pragma unroll
        for (int off = 32; off >= 1; off >>= 1) ad += __shfl_xor(ad, off, 64);
        if (lane64 == 0) inv_den[n] = 1.0f / (ad + 1e-9f);
    }
}

// ---------------- Node mid: fold w1m into PHI -> PHIw16 ----------------
__global__ __launch_bounds__(256) void node_mid_kernel(
    const float* __restrict__ beta_den,
    const float* __restrict__ sum_num,
    const hf* __restrict__ PHI16,
    hf* __restrict__ PHIw16,
    int nNodes)
{
    const int wav = threadIdx.x >> 6;
    const int lane = threadIdx.x & 63;
    for (int n = blockIdx.x * 4 + wav; n < nNodes; n += gridDim.x * 4) {
        const float st = sum_num[n] / (beta_den[n] + 1e-9f);
        const float d = -logf(st + 1e-8f);
        const float w1m = 1.0f - 1.0f / (1.0f + __expf(-(d - 0.5f)));
        const size_t idx = (size_t)n * D + lane;
        PHIw16[idx] = (hf)((float)PHI16[idx] * w1m);
    }
}

// ---------------- Fused: gather m_att + final matmuls + relu + residual + LN ----------------
__global__ __launch_bounds__(512) void final_fused_kernel(
    const int* __restrict__ rowstart,
    const int* __restrict__ src_sorted,
    const float* __restrict__ alpha_sorted,
    const float* __restrict__ inv_den,
    const hf* __restrict__ PHIw16,
    const float* __restrict__ h,
    const float* __restrict__ W_self_w, const float* __restrict__ W_self_b,
    const float* __restrict__ W_A_w,    const float* __restrict__ W_A_b,
    const float* __restrict__ W_str_w,  const float* __restrict__ W_str_b,
    const float* __restrict__ ln_g,     const float* __restrict__ ln_b,
    float* __restrict__ out,
    int nNodes)
{
    __shared__ hf2 sWs2[32][D];     // 8 KB
    __shared__ hf2 sWa2[32][D];     // 8 KB
    __shared__ float sWstr[6 * D];
    __shared__ float sBias[D];
    __shared__ float sG[D], sB[D];
    __shared__ hf hrowh[8][D];
    __shared__ hf mrowh[8][D];

    const int tid = threadIdx.x;
    for (int idx = tid; idx < 32 * D; idx += 512) {
        const int k2 = idx >> 6, j = idx & 63;
        sWs2[k2][j] = hf2{(hf)W_self_w[(2 * k2) * D + j], (hf)W_self_w[(2 * k2 + 1) * D + j]};
        sWa2[k2][j] = hf2{(hf)W_A_w[(2 * k2) * D + j],    (hf)W_A_w[(2 * k2 + 1) * D + j]};
    }
    for (int i = tid; i < 6 * D; i += 512) sWstr[i] = W_str_w[i];
    if (tid < D) {
        sBias[tid] = W_self_b[tid] + W_A_b[tid] + W_str_b[tid];
        sG[tid] = ln_g[tid];
        sB[tid] = ln_b[tid];
    }
    __syncthreads();

    const int g = tid >> 6, j = tid & 63;
    for (int n0 = blockIdx.x * 8; n0 < nNodes; n0 += gridDim.x * 8) {
        const int n = n0 + g;
        float hj = 0.f;
        __syncthreads();
        if (n < nNodes) {
            const int beg = rowstart[n];
            const int end = rowstart[n + 1];
            float acc = 0.f;
            int k = beg;
            for (; k + 7 < end; k += 8) {
                const int s0 = src_sorted[k],     s1 = src_sorted[k + 1];
                const int s2 = src_sorted[k + 2], s3 = src_sorted[k + 3];
                const int s4 = src_sorted[k + 4], s5 = src_sorted[k + 5];
                const int s6i = src_sorted[k + 6], s7 = src_sorted[k + 7];
                const float c0 = alpha_sorted[k],     c1 = alpha_sorted[k + 1];
                const float c2 = alpha_sorted[k + 2], c3 = alpha_sorted[k + 3];
                const float c4 = alpha_sorted[k + 4], c5 = alpha_sorted[k + 5];
                const float c6 = alpha_sorted[k + 6], c7 = alpha_sorted[k + 7];
                const float p0 = (float)PHIw16[(size_t)s0 * D + j];
                const float p1 = (float)PHIw16[(size_t)s1 * D + j];
                const float p2 = (float)PHIw16[(size_t)s2 * D + j];
                const float p3 = (float)PHIw16[(size_t)s3 * D + j];
                const float p4 = (float)PHIw16[(size_t)s4 * D + j];
                const float p5 = (float)PHIw16[(size_t)s5 * D + j];
                const float p6 = (float)PHIw16[(size_t)s6i * D + j];
                const float p7 = (float)PHIw16[(size_t)s7 * D + j];
                acc += c0 * p0 + c1 * p1 + c2 * p2 + c3 * p3
                     + c4 * p4 + c5 * p5 + c6 * p6 + c7 * p7;
            }
            for (; k + 3 < end; k += 4) {
                const int s0 = src_sorted[k],     s1 = src_sorted[k + 1];
                const int s2 = src_sorted[k + 2], s3 = src_sorted[k + 3];
                const float c0 = alpha_sorted[k],     c1 = alpha_sorted[k + 1];
                const float c2 = alpha_sorted[k + 2], c3 = alpha_sorted[k + 3];
                const float p0 = (float)PHIw16[(size_t)s0 * D + j];
                const float p1 = (float)PHIw16[(size_t)s1 * D + j];
                const float p2 = (float)PHIw16[(size_t)s2 * D + j];
                const float p3 = (float)PHIw16[(size_t)s3 * D + j];
                acc += c0 * p0 + c1 * p1 + c2 * p2 + c3 * p3;
            }
            for (; k < end; ++k)
                acc += alpha_sorted[k] * (float)PHIw16[(size_t)src_sorted[k] * D + j];

            hj = h[(size_t)n * D + j];
            hrowh[g][j] = (hf)hj;
            mrowh[g][j] = (hf)(acc * inv_den[n]);
        }
        __syncthreads();
        if (n < nNodes) {
            float acc = sBias[j];
            const hf2* hr = (const hf2*)hrowh[g];
            const hf2* mr = (const hf2*)mrowh[g];
            #pragma unroll
            for (int k2 = 0; k2 < 32; ++k2) {
                acc = fdot2f(sWs2[k2][j], hr[k2], acc);
                acc = fdot2f(sWa2[k2][j], mr[k2], acc);
            }
            #pragma unroll
            for (int k = 0; k < 6; ++k)
                acc += (float)hrowh[g][k] * sWstr[k * D + j];

            float pre = fmaxf(acc, 0.f) + hj;

            float mu = pre;
            #pragma unroll
            for (int off = 32; off >= 1; off >>= 1) mu += __shfl_xor(mu, off, 64);
            mu *= (1.0f / 64.0f);
            const float diff = pre - mu;
            float v = diff * diff;
            #pragma unroll
            for (int off = 32; off >= 1; off >>= 1) v += __shfl_xor(v, off, 64);
            v *= (1.0f / 64.0f);
            out[(size_t)n * D + j] = diff * rsqrtf(v + 1e-5f) * sG[j] + sB[j];
        }
    }
}

extern "C" void kernel_launch(void* const* d_in, const int* in_sizes, int n_in,
                              void* d_out, int out_size, void* d_ws, size_t ws_size,
                              hipStream_t stream) {
    const int* edge       = (const int*)d_in[0];
    const float* h        = (const float*)d_in[1];
    const float* W_att    = (const float*)d_in[2];
    const float* phi_w    = (const float*)d_in[3];
    const float* phi_b    = (const float*)d_in[4];
    const float* W_p      = (const float*)d_in[5];
    const float* W_pp     = (const float*)d_in[6];
    const float* fdef_w   = (const float*)d_in[7];
    const float* fdef_b   = (const float*)d_in[8];
    const float* W_self_w = (const float*)d_in[9];
    const float* W_self_b = (const float*)d_in[10];
    const float* W_A_w    = (const float*)d_in[11];
    const float* W_A_b    = (const float*)d_in[12];
    const float* W_str_w  = (const float*)d_in[13];
    const float* W_str_b  = (const float*)d_in[14];
    const float* ln_g     = (const float*)d_in[15];
    const float* ln_b     = (const float*)d_in[16];

    const int E = in_sizes[0] / 2;
    const int nNodes = in_sizes[1] / D;
    const int* srcI = edge;
    const int* tgtI = edge + E;

    char* ws = (char*)d_ws;
    size_t off = 0;
    auto alloc = [&](size_t bytes) { char* p = ws + off; off = (off + bytes + 255) & ~(size_t)255; return p; };

    int*    cnt       = (int*)   alloc((size_t)nNodes * 4);
    float*  beta_den  = (float*) alloc((size_t)nNodes * 4);
    float*  sum_num   = (float*) alloc((size_t)nNodes * 4);
    const size_t zero_bytes = off;
    hf2*    AP16      = (hf2*)   alloc((size_t)nNodes * D * 4);
    hf*     s6        = (hf*)    alloc((size_t)nNodes * 8 * 2);
    hf*     PP16      = (hf*)    alloc((size_t)nNodes * D * 2);
    hf*     PHI16     = (hf*)    alloc((size_t)nNodes * D * 2);
    hf*     PHIw16    = (hf*)    alloc((size_t)nNodes * D * 2);
    float*  psi       = (float*) alloc((size_t)nNodes * 4);
    float*  inv_den   = (float*) alloc((size_t)nNodes * 4);
    int*    rank      = (int*)   alloc((size_t)E * 4);
    int*    rowstart  = (int*)   alloc(((size_t)nNodes + 1) * 4);
    int*    src_sorted= (int*)   alloc((size_t)E * 4);
    float*  alpha_sorted = (float*)alloc((size_t)E * 4);

    hipMemsetAsync(d_ws, 0, zero_bytes, stream);

    node_pre_kernel<<<2048, 512, 0, stream>>>(
        h, W_att, W_p, W_pp, phi_w, phi_b, fdef_w, fdef_b,
        AP16, s6, PP16, PHI16, psi, nNodes);

    hist_kernel<<<(E + 255) / 256, 256, 0, stream>>>(tgtI, cnt, rank, E);

    scan_kernel<<<1, 1024, 0, stream>>>(cnt, rowstart, nNodes, E);

    scatter_src_kernel<<<(E + 255) / 256, 256, 0, stream>>>(
        srcI, tgtI, rank, rowstart, src_sorted, E);

    pass1_csr_kernel<<<(nNodes + 3) / 4, 256, 0, stream>>>(
        rowstart, src_sorted, h, AP16, s6, PP16, psi,
        alpha_sorted, inv_den, beta_den, sum_num, nNodes);

    node_mid_kernel<<<(nNodes + 3) / 4, 256, 0, stream>>>(
        beta_den, sum_num, PHI16, PHIw16, nNodes);

    final_fused_kernel<<<2048, 512, 0, stream>>>(
        rowstart, src_sorted, alpha_sorted, inv_den, PHIw16, h,
        W_self_w, W_self_b, W_A_w, W_A_b, W_str_w, W_str_b,
        ln_g, ln_b, (float*)d_out, nNodes);
}